// Round 11
// baseline (2689.565 us; speedup 1.0000x reference)
//
#include <hip/hip_runtime.h>
#include <hip/hip_bf16.h>

#define B_ 128
#define T_ 256
#define DV 512
#define H_ 1024
#define C_ 512

typedef _Float16 half8 __attribute__((ext_vector_type(8)));
typedef _Float16 half4 __attribute__((ext_vector_type(4)));
typedef float f32x4 __attribute__((ext_vector_type(4)));
typedef int i32x4 __attribute__((ext_vector_type(4)));
typedef unsigned long long ull;
typedef unsigned long long ull2 __attribute__((ext_vector_type(2)));

#define SENT 0x7C007C007C007C00ULL   // 4x fp16 +inf: impossible as tanh output

__device__ __forceinline__ float sigmoidf_(float x){ return 1.f/(1.f+__expf(-x)); }
__device__ __forceinline__ float tanhf_(float x){
  x = fminf(12.f, fmaxf(-12.f, x));
  float e = __expf(2.f*x);
  return (e-1.f)/(e+1.f);
}
__device__ __forceinline__ f32x4 mfma16(half8 a, half8 b, f32x4 c){
  return __builtin_amdgcn_mfma_f32_16x16x32_f16(a, b, c, 0, 0, 0);
}
__device__ __forceinline__ bool ok8(ull v){
  return ((unsigned)v & 0xFFFFu) != 0x7C00u;
}

// ---------------- pre-kernels ----------------

__global__ void k_transpose_x(const int* __restrict__ x, int* __restrict__ xT){
  int idx = blockIdx.x*256 + threadIdx.x;
  int t = idx >> 7, b = idx & 127;
  xT[idx] = x[b*T_ + t];
}

// PT_g[token][h] = sum_d W_g[h][d] * embed[token][d]
__global__ __launch_bounds__(256) void k_compute_PT(
    const float* __restrict__ embed,
    const float* __restrict__ Wz, const float* __restrict__ Wr, const float* __restrict__ Wh,
    float* __restrict__ PT){
  const float* Wg = (blockIdx.z==0)?Wz:((blockIdx.z==1)?Wr:Wh);
  float* P = PT + (size_t)blockIdx.z*DV*H_;
  __shared__ float Et[64][17];
  __shared__ float Wt[64][17];
  int tid = threadIdx.x;
  int tok0 = blockIdx.x*64, h0 = blockIdx.y*64;
  int ty = tid>>4, tx = tid&15;
  float acc[4][4];
  #pragma unroll
  for(int i=0;i<4;i++)
    #pragma unroll
    for(int j=0;j<4;j++) acc[i][j]=0.f;
  for(int d0=0; d0<DV; d0+=16){
    __syncthreads();
    for(int i=tid;i<64*16;i+=256){
      int r=i>>4, c=i&15;
      Et[r][c] = embed[(tok0+r)*DV + d0 + c];
      Wt[r][c] = Wg[(h0+r)*DV + d0 + c];
    }
    __syncthreads();
    #pragma unroll
    for(int d=0; d<16; d++){
      float av[4], bv[4];
      #pragma unroll
      for(int i=0;i<4;i++) av[i]=Et[ty*4+i][d];
      #pragma unroll
      for(int j=0;j<4;j++) bv[j]=Wt[tx*4+j][d];
      #pragma unroll
      for(int i=0;i<4;i++)
        #pragma unroll
        for(int j=0;j<4;j++) acc[i][j] += av[i]*bv[j];
    }
  }
  #pragma unroll
  for(int i=0;i<4;i++)
    #pragma unroll
    for(int j=0;j<4;j++)
      P[(size_t)(tok0+ty*4+i)*H_ + h0 + tx*4 + j] = acc[i][j];
}

// U (fp32 [H][H]) -> fragment-major fp16: Ufrag[((g*64+rt)*32+kc)*64+lane][e]
__global__ __launch_bounds__(256) void k_build_Ufrag(
    const float* __restrict__ Uz, const float* __restrict__ Ur, const float* __restrict__ Uh,
    half8* __restrict__ Ufrag){
  int idx = blockIdx.x*256 + threadIdx.x;
  int l  = idx & 63;
  int kc = (idx>>6) & 31;
  int rt = (idx>>11) & 63;
  int g  = idx>>17;
  const float* Ug = (g==0)?Uz:((g==1)?Ur:Uh);
  int row = rt*16 + (l&15);
  int kb  = kc*32 + 4*(l>>4);
  f32x4 lo = *(const f32x4*)(Ug + (size_t)row*H_ + kb);
  f32x4 hi = *(const f32x4*)(Ug + (size_t)row*H_ + kb + 16);
  half8 o;
  o[0]=(_Float16)lo[0]; o[1]=(_Float16)lo[1]; o[2]=(_Float16)lo[2]; o[3]=(_Float16)lo[3];
  o[4]=(_Float16)hi[0]; o[5]=(_Float16)hi[1]; o[6]=(_Float16)hi[2]; o[7]=(_Float16)hi[3];
  Ufrag[idx] = o;
}

// fill a buffer with the fp16-inf sentinel pattern
__global__ void k_fill_sentinel(ull* __restrict__ p){
  p[blockIdx.x*256 + threadIdx.x] = SENT;
}

// ---------------- persistent recurrent kernel: LDS-shared column staging ----------------
// grid 128 WGs x 512 thr (8 waves). WG = (c = bid&7, rb = bid>>3): rows [rb*64, +64),
// cols [c*16, +16). Wave w: rtl = w>>1 (4 row tiles), ks = w&1 (K half).
// Per step the WG stages its column's FULL h tile (32 KB) into LDS once via a
// PIPELINED sentinel data-poll (two 8-load batches alternate; counted vmcnt at
// the use point keeps polls in flight while checking -> detect lag ~0.5 RTT).
// Re-sentinel of the h_{t+2} home slot right after the stage barrier (safe:
// observing full h_t transitively proves all column readers of h_{t-1} done)
// so its IC drain overlaps MFMA+reduction+epilogue. U register-resident.
__global__ __launch_bounds__(512, 2) void k_gru_persist(
    const half8* __restrict__ Ufrag,
    const float* __restrict__ PT,
    const int* __restrict__ xT,
    half8* __restrict__ hbuf0,
    half8* __restrict__ hbuf1,
    half8* __restrict__ hbuf2)
{
  __shared__ half8 hs[2048];          // 32 KB: full column h tile, fragment-major [kc][lane]
  __shared__ f32x4 sA[4][3][64];      // 12 KB: partials from ks=1 waves

  const int tid = threadIdx.x, lane = tid & 63, w = tid >> 6;
  const int wg  = blockIdx.x;
  const int c   = wg & 7;             // column tile
  const int rb  = wg >> 3;            // row block (64 rows)
  const int rtl = w >> 1;             // 0..3
  const int rt  = rb*4 + rtl;         // global row tile 0..63
  const int ks  = w & 1;              // K half
  const int kh  = rt >> 1;            // k-chunk holding our rows' h_old

  half8 u[3][16];
  #pragma unroll
  for (int g=0; g<3; ++g)
    #pragma unroll
    for (int j=0; j<16; ++j)
      u[g][j] = Ufrag[(((g*64+rt)*32) + ks*16 + j)*64 + lane];

  const int col = c*16 + (lane & 15);
  const int q = lane >> 4;
  const int rowq = rt*16 + 4*q;
  const float* PTz = PT;
  const float* PTr = PT + (size_t)DV*H_;
  const float* PTh = PT + (size_t)2*DV*H_;

  const half8* pa = hbuf0;  // h_t
  const half8* pb = hbuf1;  // h_{t+1}
  const half8* pc = hbuf2;  // h_{t+2}

  for (int t=0; t<T_; ++t){
    // PT gather: independent of h; issued before the poll (latency hidden)
    f32x4 pz={0,0,0,0}, pr={0,0,0,0}, ph={0,0,0,0};
    if (ks == 0){
      int token = xT[t*B_ + col];
      pz = *(const f32x4*)(PTz + (size_t)token*H_ + rowq);
      pr = *(const f32x4*)(PTr + (size_t)token*H_ + rowq);
      ph = *(const f32x4*)(PTh + (size_t)token*H_ + rowq);
    }

    // ---- stage: PIPELINED sentinel data-poll of this thread's 4 chunks ----
    const ull* srcp[4];
    #pragma unroll
    for (int s=0; s<4; ++s){
      int i = tid + s*512;
      srcp[s] = (const ull*)pa + (((size_t)((i>>6)*8 + c)*64 + (i&63)) << 1);
    }
    ull cva[4], cvb[4];       // final chunk values (lo, hi per chunk)
    ull va[8], vb[8];         // two in-flight poll batches
    unsigned miss = 0xFu;
    #pragma unroll
    for (int s=0; s<4; ++s){
      va[2*s]   = __hip_atomic_load(srcp[s],   __ATOMIC_RELAXED, __HIP_MEMORY_SCOPE_AGENT);
      va[2*s+1] = __hip_atomic_load(srcp[s]+1, __ATOMIC_RELAXED, __HIP_MEMORY_SCOPE_AGENT);
    }
    int guard = 0;
    while (guard < (1<<13)){
      // issue batch B, then check batch A (A's use -> counted vmcnt, B stays in flight)
      #pragma unroll
      for (int s=0; s<4; ++s){
        vb[2*s]   = __hip_atomic_load(srcp[s],   __ATOMIC_RELAXED, __HIP_MEMORY_SCOPE_AGENT);
        vb[2*s+1] = __hip_atomic_load(srcp[s]+1, __ATOMIC_RELAXED, __HIP_MEMORY_SCOPE_AGENT);
      }
      #pragma unroll
      for (int s=0; s<4; ++s){
        if (miss & (1u<<s)){
          ull a = va[2*s], b = va[2*s+1];
          if (ok8(a) && ok8(b)){ cva[s] = a; cvb[s] = b; miss &= ~(1u<<s); }
        }
      }
      ++guard;
      if (!miss) break;
      // issue batch A, then check batch B
      #pragma unroll
      for (int s=0; s<4; ++s){
        va[2*s]   = __hip_atomic_load(srcp[s],   __ATOMIC_RELAXED, __HIP_MEMORY_SCOPE_AGENT);
        va[2*s+1] = __hip_atomic_load(srcp[s]+1, __ATOMIC_RELAXED, __HIP_MEMORY_SCOPE_AGENT);
      }
      #pragma unroll
      for (int s=0; s<4; ++s){
        if (miss & (1u<<s)){
          ull a = vb[2*s], b = vb[2*s+1];
          if (ok8(a) && ok8(b)){ cva[s] = a; cvb[s] = b; miss &= ~(1u<<s); }
        }
      }
      ++guard;
      if (!miss) break;
    }
    #pragma unroll
    for (int s=0; s<4; ++s){
      ull2 wv; wv[0] = cva[s]; wv[1] = cvb[s];
      hs[tid + s*512] = __builtin_bit_cast(half8, wv);
    }
    __syncthreads();   // #1: tile staged

    // re-sentinel the h_{t+2} home slot NOW (all column readers of its old
    // content provably done). Drains under MFMA/reduction/epilogue.
    size_t slot = (((size_t)(kh*8 + c)*64 + lane) << 1) | (unsigned)(rt & 1);
    if (ks == 0)
      __hip_atomic_store((ull*)pc + slot, SENT, __ATOMIC_RELAXED, __HIP_MEMORY_SCOPE_AGENT);

    // ---- MFMA phase: B fragments from LDS ----
    f32x4 az={0,0,0,0}, ar={0,0,0,0}, ah={0,0,0,0};
    #pragma unroll
    for (int j=0; j<16; ++j){
      half8 b = hs[(ks*16 + j)*64 + lane];
      az = mfma16(u[0][j], b, az);
      ar = mfma16(u[1][j], b, ar);
      ah = mfma16(u[2][j], b, ah);
    }
    half8 hold = {};
    if (ks == 0) hold = hs[kh*64 + lane];   // h_old, read before sync #2

    if (ks == 1){
      sA[rtl][0][lane] = az;
      sA[rtl][1][lane] = ar;
      sA[rtl][2][lane] = ah;
    }
    __syncthreads();   // #2: partials ready; all hs reads complete

    if (ks == 0){
      az += sA[rtl][0][lane];
      ar += sA[rtl][1][lane];
      ah += sA[rtl][2][lane];

      half4 ho;
      #pragma unroll
      for (int r=0; r<4; ++r){
        float z  = sigmoidf_(pz[r] + az[r]);
        float rr = sigmoidf_(pr[r] + ar[r]);
        float hh = tanhf_(ph[r] + rr*ah[r]);
        float hp = (float)hold[(rt&1)*4 + r];
        float hn = tanhf_(z*hp + (1.f-z)*hh);
        ho[r] = (_Float16)hn;
      }
      ull hval = __builtin_bit_cast(ull, ho);
      asm volatile("s_waitcnt vmcnt(0)" ::: "memory");   // sentinel long since drained
      __hip_atomic_store((ull*)pb + slot, hval, __ATOMIC_RELAXED, __HIP_MEMORY_SCOPE_AGENT);
    }
    const half8* tmp = pa; pa = pb; pb = pc; pc = tmp;   // rotate 3 buffers
  }
}

// ---------------- fallback per-step kernel ----------------
__global__ __launch_bounds__(256,1) void k_step(
    int t,
    const half8* __restrict__ hin,
    half8* __restrict__ hout,
    const half8* __restrict__ Ufrag,
    const float* __restrict__ PTz, const float* __restrict__ PTr, const float* __restrict__ PTh,
    const int* __restrict__ xT){
  int tid  = threadIdx.x;
  int lane = tid & 63;
  int w    = tid >> 6;
  int rp   = blockIdx.x;
  int ct   = blockIdx.y*4 + w;
  int rt0  = rp*2;

  f32x4 az0={0,0,0,0}, az1={0,0,0,0};
  f32x4 ar0={0,0,0,0}, ar1={0,0,0,0};
  f32x4 ah0={0,0,0,0}, ah1={0,0,0,0};
  half8 hold = {};

  #pragma unroll 4
  for(int kc=0; kc<32; ++kc){
    half8 b = hin[(kc*8 + ct)*64 + lane];
    half8 a;
    a = Ufrag[(((0*64 + rt0  )*32 + kc)<<6) + lane]; az0 = mfma16(a,b,az0);
    a = Ufrag[(((0*64 + rt0+1)*32 + kc)<<6) + lane]; az1 = mfma16(a,b,az1);
    a = Ufrag[(((1*64 + rt0  )*32 + kc)<<6) + lane]; ar0 = mfma16(a,b,ar0);
    a = Ufrag[(((1*64 + rt0+1)*32 + kc)<<6) + lane]; ar1 = mfma16(a,b,ar1);
    a = Ufrag[(((2*64 + rt0  )*32 + kc)<<6) + lane]; ah0 = mfma16(a,b,ah0);
    a = Ufrag[(((2*64 + rt0+1)*32 + kc)<<6) + lane]; ah1 = mfma16(a,b,ah1);
    if(kc == rp) hold = b;
  }

  int col   = ct*16 + (lane&15);
  int token = xT[t*B_ + col];
  int q     = lane>>4;
  half8 ho;
  #pragma unroll
  for(int tl=0; tl<2; ++tl){
    int rowq = rp*32 + tl*16 + 4*q;
    f32x4 pz = *(const f32x4*)(PTz + (size_t)token*H_ + rowq);
    f32x4 pr = *(const f32x4*)(PTr + (size_t)token*H_ + rowq);
    f32x4 ph = *(const f32x4*)(PTh + (size_t)token*H_ + rowq);
    f32x4 vz = tl ? az1 : az0;
    f32x4 vr = tl ? ar1 : ar0;
    f32x4 vh = tl ? ah1 : ah0;
    #pragma unroll
    for(int r=0;r<4;++r){
      float z  = sigmoidf_(pz[r] + vz[r]);
      float rr = sigmoidf_(pr[r] + vr[r]);
      float hh = tanhf_(ph[r] + rr*vh[r]);
      float hp = (float)hold[tl*4+r];
      float hn = tanhf_(z*hp + (1.f-z)*hh);
      ho[tl*4+r] = (_Float16)hn;
    }
  }
  hout[(rp*8 + ct)*64 + lane] = ho;
}

// ---------------- epilogue ----------------

__global__ void k_unfrag(const _Float16* __restrict__ hf, float* __restrict__ hlin){
  int idx = blockIdx.x*256 + threadIdx.x;  // idx = i*128 + b
  int b = idx & 127, i = idx >> 7;
  int kc = i>>5, kr = i&31;
  int l = ((kr>>2)&3)*16 + (b&15);
  int e = (kr>>4)*4 + (kr&3);
  int ct = b>>4;
  hlin[idx] = (float)hf[(((kc*8+ct)*64 + l)<<3) + e];
}

__global__ __launch_bounds__(256) void k_out_gemm(
    const float* __restrict__ hlin, const float* __restrict__ Wph,
    const float* __restrict__ bp, float* __restrict__ yT){
  __shared__ float hsm[64][128];
  int tid = threadIdx.x;
  int c0 = blockIdx.x*16;
  int cl = tid>>4, bg = tid&15;
  float acc[8] = {0,0,0,0,0,0,0,0};
  for(int i0=0;i0<H_;i0+=64){
    __syncthreads();
    for(int i=tid;i<64*128;i+=256){
      int r=i>>7, b=i&127;
      hsm[r][b] = hlin[(i0+r)*B_ + b];
    }
    __syncthreads();
    for(int il=0; il<64; ++il){
      float wv = Wph[(size_t)(c0+cl)*H_ + i0 + il];
      const float* hrow = &hsm[il][bg*8];
      #pragma unroll
      for(int j=0;j<8;++j) acc[j] += wv * hrow[j];
    }
  }
  float bias = bp[c0+cl];
  #pragma unroll
  for(int j=0;j<8;++j){
    int b = bg*8+j;
    yT[(size_t)b*C_ + c0+cl] = acc[j] + bias;
  }
}

__global__ __launch_bounds__(256) void k_logsoftmax(const float* __restrict__ yT, float* __restrict__ out){
  __shared__ float red[256];
  int b = blockIdx.x, tid = threadIdx.x;
  float v0 = yT[(size_t)b*C_ + tid];
  float v1 = yT[(size_t)b*C_ + 256 + tid];
  red[tid] = fmaxf(v0,v1); __syncthreads();
  for(int s=128;s>0;s>>=1){ if(tid<s) red[tid]=fmaxf(red[tid],red[tid+s]); __syncthreads(); }
  float M = red[0]; __syncthreads();
  red[tid] = __expf(v0-M)+__expf(v1-M); __syncthreads();
  for(int s=128;s>0;s>>=1){ if(tid<s) red[tid]+=red[tid+s]; __syncthreads(); }
  float L = M + logf(red[0]);
  out[(size_t)b*C_ + tid]       = v0 - L;
  out[(size_t)b*C_ + 256 + tid] = v1 - L;
}

// ---------------- launcher ----------------

extern "C" void kernel_launch(void* const* d_in, const int* in_sizes, int n_in,
                              void* d_out, int out_size, void* d_ws, size_t ws_size,
                              hipStream_t stream){
  const int*   x    = (const int*)  d_in[0];
  const float* embed= (const float*)d_in[1];
  const float* Wz   = (const float*)d_in[2];
  const float* Uz   = (const float*)d_in[3];
  const float* Wr   = (const float*)d_in[4];
  const float* Ur   = (const float*)d_in[5];
  const float* Wh   = (const float*)d_in[6];
  const float* Uh   = (const float*)d_in[7];
  const float* Wph  = (const float*)d_in[8];
  const float* bp   = (const float*)d_in[9];
  float* out = (float*)d_out;

  char* w = (char*)d_ws;
  float*    PT    = (float*)(w);                                // 6 MB
  half8*    Ufrag = (half8*)(w + (6u<<20));                      // 6 MB
  _Float16* hbuf0 = (_Float16*)(w + (12u<<20));                  // 256 KB
  _Float16* hbuf1 = (_Float16*)(w + (12u<<20) + (256u<<10));     // 256 KB
  _Float16* hbuf2 = (_Float16*)(w + (12u<<20) + (512u<<10));     // 256 KB
  int*      xT    = (int*)(w + (12u<<20) + (768u<<10));          // 128 KB
  float*    hlin  = (float*)(w + (12u<<20) + (896u<<10));        // 512 KB
  float*    yT    = (float*)(w + (12u<<20) + (1408u<<10));       // 256 KB

  k_transpose_x<<<128,256,0,stream>>>(x, xT);
  k_compute_PT<<<dim3(8,16,3),256,0,stream>>>(embed, Wz, Wr, Wh, PT);
  k_build_Ufrag<<<1536,256,0,stream>>>(Uz, Ur, Uh, Ufrag);
  (void)hipMemsetAsync(hbuf0, 0, 256u<<10, stream);             // h_0 = 0 (valid data)
  k_fill_sentinel<<<128,256,0,stream>>>((ull*)hbuf1);           // h_1 home: sentinel
  k_fill_sentinel<<<128,256,0,stream>>>((ull*)hbuf2);           // h_2 home: sentinel

  const half8* Ufrag_c = (const half8*)Ufrag;
  const float* PT_c = PT;
  const int*   xT_c = xT;
  half8* h0p = (half8*)hbuf0;
  half8* h1p = (half8*)hbuf1;
  half8* h2p = (half8*)hbuf2;
  void* args[6] = { (void*)&Ufrag_c, (void*)&PT_c, (void*)&xT_c,
                    (void*)&h0p, (void*)&h1p, (void*)&h2p };
  hipError_t ce = hipLaunchCooperativeKernel((const void*)k_gru_persist,
                                             dim3(128), dim3(512), args, 0, stream);
  if (ce != hipSuccess){
    // deterministic fallback: per-step launches, same 3-buffer rotation
    _Float16* hb[3] = {hbuf0, hbuf1, hbuf2};
    for(int t=0;t<T_;++t){
      k_step<<<dim3(32,2),256,0,stream>>>(t,
          (const half8*)hb[t%3], (half8*)hb[(t+1)%3],
          (const half8*)Ufrag,
          PT, PT + (size_t)DV*H_, PT + (size_t)2*DV*H_, xT);
    }
  }

  // h_256 lives in buf[256 % 3] = hbuf1 (both paths)
  k_unfrag<<<512,256,0,stream>>>(hbuf1, hlin);
  k_out_gemm<<<32,256,0,stream>>>(hlin, Wph, bp, yT);
  k_logsoftmax<<<128,256,0,stream>>>(yT, out);
}

// Round 12
// 1198.447 us; speedup vs baseline: 2.2442x; 2.2442x over previous
//
#include <hip/hip_runtime.h>
#include <hip/hip_bf16.h>

#define B_ 128
#define T_ 256
#define DV 512
#define H_ 1024
#define C_ 512

typedef _Float16 half8 __attribute__((ext_vector_type(8)));
typedef _Float16 half4 __attribute__((ext_vector_type(4)));
typedef float f32x4 __attribute__((ext_vector_type(4)));
typedef unsigned long long ull;
typedef unsigned long long ull2 __attribute__((ext_vector_type(2)));

#define SENT 0x7C007C007C007C00ULL   // 4x fp16 +inf: impossible as tanh output

__device__ __forceinline__ float sigmoidf_(float x){ return 1.f/(1.f+__expf(-x)); }
__device__ __forceinline__ float tanhf_(float x){
  x = fminf(12.f, fmaxf(-12.f, x));
  float e = __expf(2.f*x);
  return (e-1.f)/(e+1.f);
}
__device__ __forceinline__ f32x4 mfma16(half8 a, half8 b, f32x4 c){
  return __builtin_amdgcn_mfma_f32_16x16x32_f16(a, b, c, 0, 0, 0);
}
__device__ __forceinline__ bool ok8(ull v){
  return ((unsigned)v & 0xFFFFu) != 0x7C00u;
}

// ---------------- pre-kernels ----------------

__global__ void k_transpose_x(const int* __restrict__ x, int* __restrict__ xT){
  int idx = blockIdx.x*256 + threadIdx.x;
  int t = idx >> 7, b = idx & 127;
  xT[idx] = x[b*T_ + t];
}

// PT_g[token][h] = sum_d W_g[h][d] * embed[token][d]
__global__ __launch_bounds__(256) void k_compute_PT(
    const float* __restrict__ embed,
    const float* __restrict__ Wz, const float* __restrict__ Wr, const float* __restrict__ Wh,
    float* __restrict__ PT){
  const float* Wg = (blockIdx.z==0)?Wz:((blockIdx.z==1)?Wr:Wh);
  float* P = PT + (size_t)blockIdx.z*DV*H_;
  __shared__ float Et[64][17];
  __shared__ float Wt[64][17];
  int tid = threadIdx.x;
  int tok0 = blockIdx.x*64, h0 = blockIdx.y*64;
  int ty = tid>>4, tx = tid&15;
  float acc[4][4];
  #pragma unroll
  for(int i=0;i<4;i++)
    #pragma unroll
    for(int j=0;j<4;j++) acc[i][j]=0.f;
  for(int d0=0; d0<DV; d0+=16){
    __syncthreads();
    for(int i=tid;i<64*16;i+=256){
      int r=i>>4, c=i&15;
      Et[r][c] = embed[(tok0+r)*DV + d0 + c];
      Wt[r][c] = Wg[(h0+r)*DV + d0 + c];
    }
    __syncthreads();
    #pragma unroll
    for(int d=0; d<16; d++){
      float av[4], bv[4];
      #pragma unroll
      for(int i=0;i<4;i++) av[i]=Et[ty*4+i][d];
      #pragma unroll
      for(int j=0;j<4;j++) bv[j]=Wt[tx*4+j][d];
      #pragma unroll
      for(int i=0;i<4;i++)
        #pragma unroll
        for(int j=0;j<4;j++) acc[i][j] += av[i]*bv[j];
    }
  }
  #pragma unroll
  for(int i=0;i<4;i++)
    #pragma unroll
    for(int j=0;j<4;j++)
      P[(size_t)(tok0+ty*4+i)*H_ + h0 + tx*4 + j] = acc[i][j];
}

// U (fp32 [H][H]) -> fragment-major fp16: Ufrag[((g*64+rt)*32+kc)*64+lane][e]
__global__ __launch_bounds__(256) void k_build_Ufrag(
    const float* __restrict__ Uz, const float* __restrict__ Ur, const float* __restrict__ Uh,
    half8* __restrict__ Ufrag){
  int idx = blockIdx.x*256 + threadIdx.x;
  int l  = idx & 63;
  int kc = (idx>>6) & 31;
  int rt = (idx>>11) & 63;
  int g  = idx>>17;
  const float* Ug = (g==0)?Uz:((g==1)?Ur:Uh);
  int row = rt*16 + (l&15);
  int kb  = kc*32 + 4*(l>>4);
  f32x4 lo = *(const f32x4*)(Ug + (size_t)row*H_ + kb);
  f32x4 hi = *(const f32x4*)(Ug + (size_t)row*H_ + kb + 16);
  half8 o;
  o[0]=(_Float16)lo[0]; o[1]=(_Float16)lo[1]; o[2]=(_Float16)lo[2]; o[3]=(_Float16)lo[3];
  o[4]=(_Float16)hi[0]; o[5]=(_Float16)hi[1]; o[6]=(_Float16)hi[2]; o[7]=(_Float16)hi[3];
  Ufrag[idx] = o;
}

// fill a buffer with the fp16-inf sentinel pattern
__global__ void k_fill_sentinel(ull* __restrict__ p){
  p[blockIdx.x*256 + threadIdx.x] = SENT;
}

// ---------------- persistent recurrent kernel: full-K waves, 1 barrier/step ----------------
// grid 128 WGs x 256 thr (4 waves). WG = (c = bid&7, rb = bid>>3): rows [rb*64,+64),
// cols [c*16,+16). Wave w -> rt = rb*4+w, FULL K (u[3][32] = 384 VGPR; at
// __launch_bounds__(256,1) each SIMD hosts 1 wave -> 512-reg budget, no spill).
// No cross-wave reduction: no sA, ONE barrier/step. hs double-buffered (WAR-safe:
// a wave's stage-write of hs[p] at t+2 is after barrier A_{t+1}, which is after
// all waves' t reads of hs[p]). Sentinel data-poll = R10's drain-and-reissue
// (R11's deeper pipeline regressed via IC contention). Re-sentinel of the
// h_{t+2} home slot right after the barrier (drains under MFMA).
__global__ __launch_bounds__(256, 1) void k_gru_persist(
    const half8* __restrict__ Ufrag,
    const float* __restrict__ PT,
    const int* __restrict__ xT,
    half8* __restrict__ hbuf0,
    half8* __restrict__ hbuf1,
    half8* __restrict__ hbuf2)
{
  __shared__ half8 hs[2][2048];       // 64 KB: double-buffered column h tile [kc][lane]

  const int tid = threadIdx.x, lane = tid & 63, w = tid >> 6;
  const int wg  = blockIdx.x;
  const int c   = wg & 7;             // column tile
  const int rb  = wg >> 3;            // row block (64 rows)
  const int rt  = rb*4 + w;           // global row tile 0..63
  const int kh  = rt >> 1;            // k-chunk holding our rows' h_old

  half8 u0[32], u1[32], u2[32];
  #pragma unroll
  for (int j=0; j<32; ++j) u0[j] = Ufrag[(((0*64+rt)*32) + j)*64 + lane];
  #pragma unroll
  for (int j=0; j<32; ++j) u1[j] = Ufrag[(((1*64+rt)*32) + j)*64 + lane];
  #pragma unroll
  for (int j=0; j<32; ++j) u2[j] = Ufrag[(((2*64+rt)*32) + j)*64 + lane];

  const int col = c*16 + (lane & 15);
  const int q = lane >> 4;
  const int rowq = rt*16 + 4*q;
  const float* PTz = PT;
  const float* PTr = PT + (size_t)DV*H_;
  const float* PTh = PT + (size_t)2*DV*H_;

  const half8* pa = hbuf0;  // h_t
  const half8* pb = hbuf1;  // h_{t+1}
  const half8* pc = hbuf2;  // h_{t+2}

  for (int t=0; t<T_; ++t){
    const int par = t & 1;

    // PT gather: independent of h; issued before the poll (latency hidden)
    int token = xT[t*B_ + col];
    f32x4 pz = *(const f32x4*)(PTz + (size_t)token*H_ + rowq);
    f32x4 pr = *(const f32x4*)(PTr + (size_t)token*H_ + rowq);
    f32x4 ph = *(const f32x4*)(PTh + (size_t)token*H_ + rowq);

    // ---- stage: sentinel data-poll of this thread's 8 chunks (R10 protocol) ----
    // chunk s: ull index = base + s*4096 (kc advances by 4 per s)
    const ull* sbase = (const ull*)pa + (((size_t)((tid>>6)*8 + c)*64 + (tid&63)) << 1);
    ull va[16];
    unsigned miss = 0xFFu;
    #pragma unroll
    for (int s=0; s<8; ++s){
      va[2*s]   = __hip_atomic_load(sbase + s*4096,     __ATOMIC_RELAXED, __HIP_MEMORY_SCOPE_AGENT);
      va[2*s+1] = __hip_atomic_load(sbase + s*4096 + 1, __ATOMIC_RELAXED, __HIP_MEMORY_SCOPE_AGENT);
    }
    #pragma unroll
    for (int s=0; s<8; ++s)
      if (ok8(va[2*s]) && ok8(va[2*s+1])) miss &= ~(1u<<s);
    int guard = 0;
    while (miss && ++guard < (1<<14)){   // small guard: fail visibly, never hang
      #pragma unroll
      for (int s=0; s<8; ++s){
        if (miss & (1u<<s)){
          va[2*s]   = __hip_atomic_load(sbase + s*4096,     __ATOMIC_RELAXED, __HIP_MEMORY_SCOPE_AGENT);
          va[2*s+1] = __hip_atomic_load(sbase + s*4096 + 1, __ATOMIC_RELAXED, __HIP_MEMORY_SCOPE_AGENT);
        }
      }
      #pragma unroll
      for (int s=0; s<8; ++s){
        if ((miss & (1u<<s)) && ok8(va[2*s]) && ok8(va[2*s+1])) miss &= ~(1u<<s);
      }
    }
    #pragma unroll
    for (int s=0; s<8; ++s){
      ull2 wv; wv[0] = va[2*s]; wv[1] = va[2*s+1];
      hs[par][tid + s*256] = __builtin_bit_cast(half8, wv);
    }
    __syncthreads();   // tile staged (single barrier per step)

    // re-sentinel the h_{t+2} home slot NOW (observing full h_t transitively
    // proves all column readers of h_{t-1} finished). Drains under MFMA.
    size_t slot = (((size_t)(kh*8 + c)*64 + lane) << 1) | (unsigned)(rt & 1);
    __hip_atomic_store((ull*)pc + slot, SENT, __ATOMIC_RELAXED, __HIP_MEMORY_SCOPE_AGENT);

    // ---- MFMA phase: full K from LDS ----
    f32x4 az={0,0,0,0}, ar={0,0,0,0}, ah={0,0,0,0};
    #pragma unroll
    for (int j=0; j<32; ++j){
      half8 b = hs[par][j*64 + lane];
      az = mfma16(u0[j], b, az);
      ar = mfma16(u1[j], b, ar);
      ah = mfma16(u2[j], b, ah);
    }
    half4 hold = ((half4*)hs[par])[((kh*64 + lane) << 1) | (rt & 1)];

    // ---- epilogue (per wave, no cross-wave reduction) ----
    half4 ho;
    #pragma unroll
    for (int r=0; r<4; ++r){
      float z  = sigmoidf_(pz[r] + az[r]);
      float rr = sigmoidf_(pr[r] + ar[r]);
      float hh = tanhf_(ph[r] + rr*ah[r]);
      float hp = (float)hold[r];
      float hn = tanhf_(z*hp + (1.f-z)*hh);
      ho[r] = (_Float16)hn;
    }
    ull hval = __builtin_bit_cast(ull, ho);
    asm volatile("s_waitcnt vmcnt(0)" ::: "memory");   // prior sentinel to this buffer drained
    __hip_atomic_store((ull*)pb + slot, hval, __ATOMIC_RELAXED, __HIP_MEMORY_SCOPE_AGENT);

    const half8* tmp = pa; pa = pb; pb = pc; pc = tmp;   // rotate 3 buffers
  }
}

// ---------------- fallback per-step kernel ----------------
__global__ __launch_bounds__(256,1) void k_step(
    int t,
    const half8* __restrict__ hin,
    half8* __restrict__ hout,
    const half8* __restrict__ Ufrag,
    const float* __restrict__ PTz, const float* __restrict__ PTr, const float* __restrict__ PTh,
    const int* __restrict__ xT){
  int tid  = threadIdx.x;
  int lane = tid & 63;
  int w    = tid >> 6;
  int rp   = blockIdx.x;
  int ct   = blockIdx.y*4 + w;
  int rt0  = rp*2;

  f32x4 az0={0,0,0,0}, az1={0,0,0,0};
  f32x4 ar0={0,0,0,0}, ar1={0,0,0,0};
  f32x4 ah0={0,0,0,0}, ah1={0,0,0,0};
  half8 hold = {};

  #pragma unroll 4
  for(int kc=0; kc<32; ++kc){
    half8 b = hin[(kc*8 + ct)*64 + lane];
    half8 a;
    a = Ufrag[(((0*64 + rt0  )*32 + kc)<<6) + lane]; az0 = mfma16(a,b,az0);
    a = Ufrag[(((0*64 + rt0+1)*32 + kc)<<6) + lane]; az1 = mfma16(a,b,az1);
    a = Ufrag[(((1*64 + rt0  )*32 + kc)<<6) + lane]; ar0 = mfma16(a,b,ar0);
    a = Ufrag[(((1*64 + rt0+1)*32 + kc)<<6) + lane]; ar1 = mfma16(a,b,ar1);
    a = Ufrag[(((2*64 + rt0  )*32 + kc)<<6) + lane]; ah0 = mfma16(a,b,ah0);
    a = Ufrag[(((2*64 + rt0+1)*32 + kc)<<6) + lane]; ah1 = mfma16(a,b,ah1);
    if(kc == rp) hold = b;
  }

  int col   = ct*16 + (lane&15);
  int token = xT[t*B_ + col];
  int q     = lane>>4;
  half8 ho;
  #pragma unroll
  for(int tl=0; tl<2; ++tl){
    int rowq = rp*32 + tl*16 + 4*q;
    f32x4 pz = *(const f32x4*)(PTz + (size_t)token*H_ + rowq);
    f32x4 pr = *(const f32x4*)(PTr + (size_t)token*H_ + rowq);
    f32x4 ph = *(const f32x4*)(PTh + (size_t)token*H_ + rowq);
    f32x4 vz = tl ? az1 : az0;
    f32x4 vr = tl ? ar1 : ar0;
    f32x4 vh = tl ? ah1 : ah0;
    #pragma unroll
    for(int r=0;r<4;++r){
      float z  = sigmoidf_(pz[r] + vz[r]);
      float rr = sigmoidf_(pr[r] + vr[r]);
      float hh = tanhf_(ph[r] + rr*vh[r]);
      float hp = (float)hold[tl*4+r];
      float hn = tanhf_(z*hp + (1.f-z)*hh);
      ho[tl*4+r] = (_Float16)hn;
    }
  }
  hout[(rp*8 + ct)*64 + lane] = ho;
}

// ---------------- epilogue ----------------

__global__ void k_unfrag(const _Float16* __restrict__ hf, float* __restrict__ hlin){
  int idx = blockIdx.x*256 + threadIdx.x;  // idx = i*128 + b
  int b = idx & 127, i = idx >> 7;
  int kc = i>>5, kr = i&31;
  int l = ((kr>>2)&3)*16 + (b&15);
  int e = (kr>>4)*4 + (kr&3);
  int ct = b>>4;
  hlin[idx] = (float)hf[(((kc*8+ct)*64 + l)<<3) + e];
}

__global__ __launch_bounds__(256) void k_out_gemm(
    const float* __restrict__ hlin, const float* __restrict__ Wph,
    const float* __restrict__ bp, float* __restrict__ yT){
  __shared__ float hsm[64][128];
  int tid = threadIdx.x;
  int c0 = blockIdx.x*16;
  int cl = tid>>4, bg = tid&15;
  float acc[8] = {0,0,0,0,0,0,0,0};
  for(int i0=0;i0<H_;i0+=64){
    __syncthreads();
    for(int i=tid;i<64*128;i+=256){
      int r=i>>7, b=i&127;
      hsm[r][b] = hlin[(i0+r)*B_ + b];
    }
    __syncthreads();
    for(int il=0; il<64; ++il){
      float wv = Wph[(size_t)(c0+cl)*H_ + i0 + il];
      const float* hrow = &hsm[il][bg*8];
      #pragma unroll
      for(int j=0;j<8;++j) acc[j] += wv * hrow[j];
    }
  }
  float bias = bp[c0+cl];
  #pragma unroll
  for(int j=0;j<8;++j){
    int b = bg*8+j;
    yT[(size_t)b*C_ + c0+cl] = acc[j] + bias;
  }
}

__global__ __launch_bounds__(256) void k_logsoftmax(const float* __restrict__ yT, float* __restrict__ out){
  __shared__ float red[256];
  int b = blockIdx.x, tid = threadIdx.x;
  float v0 = yT[(size_t)b*C_ + tid];
  float v1 = yT[(size_t)b*C_ + 256 + tid];
  red[tid] = fmaxf(v0,v1); __syncthreads();
  for(int s=128;s>0;s>>=1){ if(tid<s) red[tid]=fmaxf(red[tid],red[tid+s]); __syncthreads(); }
  float M = red[0]; __syncthreads();
  red[tid] = __expf(v0-M)+__expf(v1-M); __syncthreads();
  for(int s=128;s>0;s>>=1){ if(tid<s) red[tid]+=red[tid+s]; __syncthreads(); }
  float L = M + logf(red[0]);
  out[(size_t)b*C_ + tid]       = v0 - L;
  out[(size_t)b*C_ + 256 + tid] = v1 - L;
}

// ---------------- launcher ----------------

extern "C" void kernel_launch(void* const* d_in, const int* in_sizes, int n_in,
                              void* d_out, int out_size, void* d_ws, size_t ws_size,
                              hipStream_t stream){
  const int*   x    = (const int*)  d_in[0];
  const float* embed= (const float*)d_in[1];
  const float* Wz   = (const float*)d_in[2];
  const float* Uz   = (const float*)d_in[3];
  const float* Wr   = (const float*)d_in[4];
  const float* Ur   = (const float*)d_in[5];
  const float* Wh   = (const float*)d_in[6];
  const float* Uh   = (const float*)d_in[7];
  const float* Wph  = (const float*)d_in[8];
  const float* bp   = (const float*)d_in[9];
  float* out = (float*)d_out;

  char* w = (char*)d_ws;
  float*    PT    = (float*)(w);                                // 6 MB
  half8*    Ufrag = (half8*)(w + (6u<<20));                      // 6 MB
  _Float16* hbuf0 = (_Float16*)(w + (12u<<20));                  // 256 KB
  _Float16* hbuf1 = (_Float16*)(w + (12u<<20) + (256u<<10));     // 256 KB
  _Float16* hbuf2 = (_Float16*)(w + (12u<<20) + (512u<<10));     // 256 KB
  int*      xT    = (int*)(w + (12u<<20) + (768u<<10));          // 128 KB
  float*    hlin  = (float*)(w + (12u<<20) + (896u<<10));        // 512 KB
  float*    yT    = (float*)(w + (12u<<20) + (1408u<<10));       // 256 KB

  k_transpose_x<<<128,256,0,stream>>>(x, xT);
  k_compute_PT<<<dim3(8,16,3),256,0,stream>>>(embed, Wz, Wr, Wh, PT);
  k_build_Ufrag<<<1536,256,0,stream>>>(Uz, Ur, Uh, Ufrag);
  (void)hipMemsetAsync(hbuf0, 0, 256u<<10, stream);             // h_0 = 0 (valid data)
  k_fill_sentinel<<<128,256,0,stream>>>((ull*)hbuf1);           // h_1 home: sentinel
  k_fill_sentinel<<<128,256,0,stream>>>((ull*)hbuf2);           // h_2 home: sentinel

  const half8* Ufrag_c = (const half8*)Ufrag;
  const float* PT_c = PT;
  const int*   xT_c = xT;
  half8* h0p = (half8*)hbuf0;
  half8* h1p = (half8*)hbuf1;
  half8* h2p = (half8*)hbuf2;
  void* args[6] = { (void*)&Ufrag_c, (void*)&PT_c, (void*)&xT_c,
                    (void*)&h0p, (void*)&h1p, (void*)&h2p };
  hipError_t ce = hipLaunchCooperativeKernel((const void*)k_gru_persist,
                                             dim3(128), dim3(256), args, 0, stream);
  if (ce != hipSuccess){
    // deterministic fallback: per-step launches, same 3-buffer rotation
    _Float16* hb[3] = {hbuf0, hbuf1, hbuf2};
    for(int t=0;t<T_;++t){
      k_step<<<dim3(32,2),256,0,stream>>>(t,
          (const half8*)hb[t%3], (half8*)hb[(t+1)%3],
          (const half8*)Ufrag,
          PT, PT + (size_t)DV*H_, PT + (size_t)2*DV*H_, xT);
    }
  }

  // h_256 lives in buf[256 % 3] = hbuf1 (both paths)
  k_unfrag<<<512,256,0,stream>>>(hbuf1, hlin);
  k_out_gemm<<<32,256,0,stream>>>(hlin, Wph, bp, yT);
  k_logsoftmax<<<128,256,0,stream>>>(yT, out);
}